// Round 1
// baseline (493.591 us; speedup 1.0000x reference)
//
#include <hip/hip_runtime.h>
#include <stdint.h>

#define TT 2048
#define HH 1024
#define II 4096
#define EE 8
#define KS 4
#define KSPAN (II / KS)

typedef __attribute__((ext_vector_type(4))) float floatx4;
typedef __attribute__((ext_vector_type(8))) __bf16 bf16x8;

// round-to-nearest-even fp32 -> bf16 (bits)
__device__ __forceinline__ unsigned short f2bf(float f) {
  union { float f; unsigned u; } v; v.f = f;
  return (unsigned short)((v.u + 0x7FFFu + ((v.u >> 16) & 1u)) >> 16);
}

// async global->LDS, 16 bytes per lane; LDS dest must be wave-uniform base + lane*16
__device__ __forceinline__ void async_ld16(const void* g, void* l) {
  __builtin_amdgcn_global_load_lds(
      (__attribute__((address_space(1))) void*)g,
      (__attribute__((address_space(3))) void*)l, 16, 0, 0);
}

// compiler-level memory reorder fence (no code emitted)
#define CFENCE asm volatile("" ::: "memory")
#define WAIT_VM(n) asm volatile("s_waitcnt vmcnt(" #n ")" ::: "memory")
#define WAIT_LGKM0 asm volatile("s_waitcnt lgkmcnt(0)" ::: "memory")

// ---------------- gating: fp32 logits, softmax top-2, renorm; emit x_bf16 ----
__global__ __launch_bounds__(256) void k_gating(
    const float* __restrict__ x, const float* __restrict__ gw,
    unsigned short* __restrict__ xb, int* __restrict__ sel_e,
    float* __restrict__ sel_w, int* __restrict__ counts) {
  int t = blockIdx.x;
  int tid = threadIdx.x;
  floatx4 xv = ((const floatx4*)(x + (size_t)t * HH))[tid];
  ushort4 xo;
  xo.x = f2bf(xv.x); xo.y = f2bf(xv.y); xo.z = f2bf(xv.z); xo.w = f2bf(xv.w);
  ((ushort4*)(xb + (size_t)t * HH))[tid] = xo;

  float part[EE];
#pragma unroll
  for (int e = 0; e < EE; e++) {
    floatx4 g = ((const floatx4*)(gw + e * HH))[tid];
    part[e] = xv.x * g.x + xv.y * g.y + xv.z * g.z + xv.w * g.w;
  }
#pragma unroll
  for (int e = 0; e < EE; e++) {
    float v = part[e];
#pragma unroll
    for (int off = 32; off > 0; off >>= 1) v += __shfl_down(v, off, 64);
    part[e] = v;
  }
  __shared__ float red[4][EE];
  int wave = tid >> 6;
  if ((tid & 63) == 0) {
#pragma unroll
    for (int e = 0; e < EE; e++) red[wave][e] = part[e];
  }
  __syncthreads();
  if (tid == 0) {
    float lg[EE];
#pragma unroll
    for (int e = 0; e < EE; e++)
      lg[e] = red[0][e] + red[1][e] + red[2][e] + red[3][e];
    int e0 = 0;
#pragma unroll
    for (int e = 1; e < EE; e++) if (lg[e] > lg[e0]) e0 = e;
    int e1 = (e0 == 0) ? 1 : 0;
#pragma unroll
    for (int e = 0; e < EE; e++) if (e != e0 && lg[e] > lg[e1]) e1 = e;
    float w0 = 1.f / (1.f + expf(lg[e1] - lg[e0]));
    sel_e[t * 2] = e0; sel_e[t * 2 + 1] = e1;
    sel_w[t * 2] = w0; sel_w[t * 2 + 1] = 1.f - w0;
    atomicAdd(&counts[e0], 1);
    atomicAdd(&counts[e1], 1);
  }
}

// ---------------- scan + fill (single block, LDS counters) ------------------
__global__ __launch_bounds__(256) void k_fill(
    const int* __restrict__ counts, const int* __restrict__ sel_e,
    const float* __restrict__ sel_w, int* __restrict__ bases,
    int* __restrict__ row_token, float* __restrict__ row_w) {
  __shared__ int lb[EE];
  __shared__ int lc[EE];
  int tid = threadIdx.x;
  if (tid == 0) {
    int s = 0;
    for (int e = 0; e < EE; e++) { lb[e] = s; s += counts[e]; }
  }
  if (tid < EE) lc[tid] = 0;
  __syncthreads();
  for (int p = tid; p < TT * 2; p += 256) {
    int e = sel_e[p];
    int slot = lb[e] + atomicAdd(&lc[e], 1);
    row_token[slot] = p >> 1;
    row_w[slot] = sel_w[p];
  }
  __syncthreads();
  if (tid < EE) bases[tid] = lb[tid];
}

// ---------------- GEMM1: hid = silu(x @ w1^T) -------------------------------
// Double-buffered LDS pipeline with counted vmcnt (never drain fresh loads),
// raw s_barrier, XOR-swizzled LDS tiles (2-way bank access on ds_read_b128).
__global__ __launch_bounds__(256) void k_gemm1(
    const unsigned short* __restrict__ xb,
    const float* __restrict__ w1,
    unsigned short* __restrict__ hid,
    const int* __restrict__ counts, const int* __restrict__ bases,
    const int* __restrict__ row_token) {
  const int e = blockIdx.z;
  const int count = counts[e];
  const int m0 = blockIdx.y * 128;
  if (m0 >= count) return;
  const int n0 = blockIdx.x * 128;
  const int base = bases[e];

  __shared__ __align__(16) unsigned short Smem[4 * 4096];  // A0 A1 B0 B1 = 32 KB
  unsigned short* const A0b = Smem;
  unsigned short* const A1b = Smem + 4096;
  unsigned short* const B0b = Smem + 8192;
  unsigned short* const B1b = Smem + 12288;

  const int tid = threadIdx.x;
  const int lane = tid & 63;
  const int wave = tid >> 6;
  const int wm = (wave & 1) * 64;
  const int wn = (wave >> 1) * 64;
  const int quad = lane >> 4;
  const int l16 = lane & 15;

  // staging geometry: tile row r = tid>>2, chunk (8 elems = 16B) index
  const int rA0 = tid >> 2;                       // rows 0..63 (and +64)
  const int swz = (tid & 3) ^ ((tid >> 3) & 3);   // XOR swizzle involution
  const int ccA = swz * 8;        // A global col (pre-swizzled source for linear DMA dest)
  const int ccB = (tid & 3) * 8;  // B global col (linear; swizzle applied at ds_write)
  const int ldsA = tid * 8;                 // linear DMA dest (shorts), +2048 for rows 64..127
  const int ldsB = rA0 * 32 + swz * 8;      // swizzled ds_write dest (shorts), +2048

  int g0 = m0 + rA0;      if (g0 > count - 1) g0 = count - 1;
  int g1 = m0 + rA0 + 64; if (g1 > count - 1) g1 = count - 1;
  const unsigned short* aS0 = xb + (size_t)row_token[base + g0] * HH + ccA;
  const unsigned short* aS1 = xb + (size_t)row_token[base + g1] * HH + ccA;
  const float* wp = w1 + (size_t)e * II * HH;
  const float* bp0 = wp + (size_t)(n0 + rA0) * HH + ccB;
  const float* bp1 = bp0 + (size_t)64 * HH;

  // precomputed swizzled fragment read offsets (shorts)
  int offA[4], offB[4];
#pragma unroll
  for (int i = 0; i < 4; i++) {
    const int Ra = wm + i * 16 + l16;
    offA[i] = Ra * 32 + 8 * (quad ^ ((Ra >> 1) & 3));
    const int Rb = wn + i * 16 + l16;
    offB[i] = Rb * 32 + 8 * (quad ^ ((Rb >> 1) & 3));
  }

  const floatx4 fz = {0.f, 0.f, 0.f, 0.f};
  floatx4 acc[4][4];
#pragma unroll
  for (int i = 0; i < 4; i++)
#pragma unroll
    for (int j = 0; j < 4; j++) acc[i][j] = fz;

  // ---- prologue: stage tile 0 into A0/B0 ----
  {
    floatx4 f0a = *(const floatx4*)(bp0);
    floatx4 f0b = *(const floatx4*)(bp0 + 4);
    floatx4 f1a = *(const floatx4*)(bp1);
    floatx4 f1b = *(const floatx4*)(bp1 + 4);
    CFENCE;
    async_ld16(aS0, A0b + ldsA);
    async_ld16(aS1, A0b + ldsA + 2048);
    CFENCE;
    WAIT_VM(2);  // B regs ready, A DMA still in flight
    bf16x8 wv0, wv1;
#pragma unroll
    for (int j = 0; j < 4; j++) {
      wv0[j] = (__bf16)f0a[j]; wv0[j + 4] = (__bf16)f0b[j];
      wv1[j] = (__bf16)f1a[j]; wv1[j + 4] = (__bf16)f1b[j];
    }
    *(bf16x8*)(B0b + ldsB) = wv0;
    *(bf16x8*)(B0b + ldsB + 2048) = wv1;
    WAIT_VM(0);   // A DMA landed
    WAIT_LGKM0;   // B writes visible
    __builtin_amdgcn_s_barrier();
  }

  unsigned short* Ac = A0b; unsigned short* An = A1b;
  unsigned short* Bc = B0b; unsigned short* Bn = B1b;

  for (int k0 = 0; k0 < HH; k0 += 32) {
    const bool has1 = (k0 + 32 < HH);
    floatx4 g0a, g0b, g1a, g1b;
    if (has1) {
      // issue next tile's loads FIRST: B regs (4 vmem) then A DMA (2 vmem)
      g0a = *(const floatx4*)(bp0 + k0 + 32);
      g0b = *(const floatx4*)(bp0 + k0 + 36);
      g1a = *(const floatx4*)(bp1 + k0 + 32);
      g1b = *(const floatx4*)(bp1 + k0 + 36);
      CFENCE;
      async_ld16(aS0 + k0 + 32, An + ldsA);
      async_ld16(aS1 + k0 + 32, An + ldsA + 2048);
      CFENCE;
    }
    bf16x8 af[4], bfr[4];
#pragma unroll
    for (int i = 0; i < 4; i++) {
      af[i]  = *(const bf16x8*)(Ac + offA[i]);
      bfr[i] = *(const bf16x8*)(Bc + offB[i]);
    }
#pragma unroll
    for (int i = 0; i < 4; i++)
#pragma unroll
      for (int j = 0; j < 4; j++)
        acc[i][j] = __builtin_amdgcn_mfma_f32_16x16x32_bf16(af[i], bfr[j], acc[i][j], 0, 0, 0);
    if (has1) {
      WAIT_VM(2);  // the 4 B loads done; 2 A DMA still flying
      bf16x8 wv0, wv1;
#pragma unroll
      for (int j = 0; j < 4; j++) {
        wv0[j] = (__bf16)g0a[j]; wv0[j + 4] = (__bf16)g0b[j];
        wv1[j] = (__bf16)g1a[j]; wv1[j + 4] = (__bf16)g1b[j];
      }
      *(bf16x8*)(Bn + ldsB) = wv0;
      *(bf16x8*)(Bn + ldsB + 2048) = wv1;
      WAIT_VM(0);  // A DMA landed (covered by ds_read+MFMA+cvt above)
    }
    WAIT_LGKM0;
    __builtin_amdgcn_s_barrier();
    { unsigned short* t = Ac; Ac = An; An = t; }
    { unsigned short* t = Bc; Bc = Bn; Bn = t; }
  }

  // epilogue: silu -> bf16 -> per-wave LDS bounce -> coalesced 16B stores.
  unsigned short* Sl = Smem + wave * (16 * 72);
#pragma unroll
  for (int i = 0; i < 4; i++) {
#pragma unroll
    for (int r = 0; r < 4; r++) {
      const int row16 = quad * 4 + r;
#pragma unroll
      for (int j = 0; j < 4; j++) {
        float z = acc[i][j][r];
        Sl[row16 * 72 + l16 + 16 * j] = f2bf(z / (1.f + __expf(-z)));
      }
    }
#pragma unroll
    for (int half = 0; half < 2; half++) {
      const int row16 = (lane >> 3) + 8 * half;
      const int m = wm + i * 16 + row16;
      if (m0 + m < count) {
        bf16x8 v = *(const bf16x8*)(Sl + row16 * 72 + (lane & 7) * 8);
        *(bf16x8*)(hid + (size_t)(base + m0 + m) * II + n0 + wn + (lane & 7) * 8) = v;
      }
    }
  }
}

// ---------------- GEMM2: out[tok] += w_slot * (hid @ w2^T), split-K atomics -
__global__ __launch_bounds__(256) void k_gemm2(
    const unsigned short* __restrict__ hid,
    const float* __restrict__ w2,
    float* __restrict__ out,
    const int* __restrict__ counts, const int* __restrict__ bases,
    const int* __restrict__ row_token, const float* __restrict__ row_w) {
  const int e = blockIdx.z;
  const int count = counts[e];
  const int m0 = blockIdx.y * 128;
  if (m0 >= count) return;
  const int nt = blockIdx.x & 7;
  const int ks = blockIdx.x >> 3;
  const int n0 = nt * 128;
  const int base = bases[e];
  const int kbeg = ks * KSPAN;

  __shared__ __align__(16) unsigned short Smem2[4 * 4096];
  unsigned short* const A0b = Smem2;
  unsigned short* const A1b = Smem2 + 4096;
  unsigned short* const B0b = Smem2 + 8192;
  unsigned short* const B1b = Smem2 + 12288;

  const int tid = threadIdx.x;
  const int lane = tid & 63;
  const int wave = tid >> 6;
  const int wm = (wave & 1) * 64;
  const int wn = (wave >> 1) * 64;
  const int quad = lane >> 4;
  const int l16 = lane & 15;

  const int rA0 = tid >> 2;
  const int swz = (tid & 3) ^ ((tid >> 3) & 3);
  const int ccA = swz * 8;
  const int ccB = (tid & 3) * 8;
  const int ldsA = tid * 8;
  const int ldsB = rA0 * 32 + swz * 8;

  int g0 = m0 + rA0;      if (g0 > count - 1) g0 = count - 1;
  int g1 = m0 + rA0 + 64; if (g1 > count - 1) g1 = count - 1;
  const unsigned short* aS0 = hid + (size_t)(base + g0) * II + kbeg + ccA;
  const unsigned short* aS1 = hid + (size_t)(base + g1) * II + kbeg + ccA;
  const float* wp = w2 + (size_t)e * HH * II;
  const float* bp0 = wp + (size_t)(n0 + rA0) * II + kbeg + ccB;
  const float* bp1 = bp0 + (size_t)64 * II;

  int offA[4], offB[4];
#pragma unroll
  for (int i = 0; i < 4; i++) {
    const int Ra = wm + i * 16 + l16;
    offA[i] = Ra * 32 + 8 * (quad ^ ((Ra >> 1) & 3));
    const int Rb = wn + i * 16 + l16;
    offB[i] = Rb * 32 + 8 * (quad ^ ((Rb >> 1) & 3));
  }

  const floatx4 fz = {0.f, 0.f, 0.f, 0.f};
  floatx4 acc[4][4];
#pragma unroll
  for (int i = 0; i < 4; i++)
#pragma unroll
    for (int j = 0; j < 4; j++) acc[i][j] = fz;

  {
    floatx4 f0a = *(const floatx4*)(bp0);
    floatx4 f0b = *(const floatx4*)(bp0 + 4);
    floatx4 f1a = *(const floatx4*)(bp1);
    floatx4 f1b = *(const floatx4*)(bp1 + 4);
    CFENCE;
    async_ld16(aS0, A0b + ldsA);
    async_ld16(aS1, A0b + ldsA + 2048);
    CFENCE;
    WAIT_VM(2);
    bf16x8 wv0, wv1;
#pragma unroll
    for (int j = 0; j < 4; j++) {
      wv0[j] = (__bf16)f0a[j]; wv0[j + 4] = (__bf16)f0b[j];
      wv1[j] = (__bf16)f1a[j]; wv1[j + 4] = (__bf16)f1b[j];
    }
    *(bf16x8*)(B0b + ldsB) = wv0;
    *(bf16x8*)(B0b + ldsB + 2048) = wv1;
    WAIT_VM(0);
    WAIT_LGKM0;
    __builtin_amdgcn_s_barrier();
  }

  unsigned short* Ac = A0b; unsigned short* An = A1b;
  unsigned short* Bc = B0b; unsigned short* Bn = B1b;

  for (int k0 = 0; k0 < KSPAN; k0 += 32) {
    const bool has1 = (k0 + 32 < KSPAN);
    floatx4 g0a, g0b, g1a, g1b;
    if (has1) {
      g0a = *(const floatx4*)(bp0 + k0 + 32);
      g0b = *(const floatx4*)(bp0 + k0 + 36);
      g1a = *(const floatx4*)(bp1 + k0 + 32);
      g1b = *(const floatx4*)(bp1 + k0 + 36);
      CFENCE;
      async_ld16(aS0 + k0 + 32, An + ldsA);
      async_ld16(aS1 + k0 + 32, An + ldsA + 2048);
      CFENCE;
    }
    bf16x8 af[4], bfr[4];
#pragma unroll
    for (int i = 0; i < 4; i++) {
      af[i]  = *(const bf16x8*)(Ac + offA[i]);
      bfr[i] = *(const bf16x8*)(Bc + offB[i]);
    }
#pragma unroll
    for (int i = 0; i < 4; i++)
#pragma unroll
      for (int j = 0; j < 4; j++)
        acc[i][j] = __builtin_amdgcn_mfma_f32_16x16x32_bf16(af[i], bfr[j], acc[i][j], 0, 0, 0);
    if (has1) {
      WAIT_VM(2);
      bf16x8 wv0, wv1;
#pragma unroll
      for (int j = 0; j < 4; j++) {
        wv0[j] = (__bf16)g0a[j]; wv0[j + 4] = (__bf16)g0b[j];
        wv1[j] = (__bf16)g1a[j]; wv1[j + 4] = (__bf16)g1b[j];
      }
      *(bf16x8*)(Bn + ldsB) = wv0;
      *(bf16x8*)(Bn + ldsB + 2048) = wv1;
      WAIT_VM(0);
    }
    WAIT_LGKM0;
    __builtin_amdgcn_s_barrier();
    { unsigned short* t = Ac; Ac = An; An = t; }
    { unsigned short* t = Bc; Bc = Bn; Bn = t; }
  }

  // epilogue: scale by routing weight, atomically accumulate into out[token].
#pragma unroll
  for (int i = 0; i < 4; i++) {
#pragma unroll
    for (int r = 0; r < 4; r++) {
      const int m = wm + i * 16 + quad * 4 + r;
      if (m0 + m < count) {
        const int slot = base + m0 + m;
        const int tok = row_token[slot];
        const float wgt = row_w[slot];
        float* op = out + (size_t)tok * HH + n0 + wn + l16;
#pragma unroll
        for (int j = 0; j < 4; j++) atomicAdd(op + j * 16, wgt * acc[i][j][r]);
      }
    }
  }
}

// ---------------- launch ----------------------------------------------------
extern "C" void kernel_launch(void* const* d_in, const int* in_sizes, int n_in,
                              void* d_out, int out_size, void* d_ws, size_t ws_size,
                              hipStream_t stream) {
  const float* x  = (const float*)d_in[0];
  const float* gw = (const float*)d_in[1];
  const float* w1 = (const float*)d_in[2];
  const float* w2 = (const float*)d_in[3];
  float* out = (float*)d_out;

  char* ws = (char*)d_ws;
  size_t off = 0;
  auto take = [&](size_t n) -> char* {
    char* p = ws + off;
    off += (n + 255) & ~(size_t)255;
    return p;
  };
  unsigned short* xb  = (unsigned short*)take((size_t)TT * HH * 2);
  unsigned short* hid = (unsigned short*)take((size_t)TT * 2 * II * 2);
  int*   counts    = (int*)take(EE * 4);
  int*   bases     = (int*)take(EE * 4);
  int*   row_token = (int*)take((size_t)TT * 2 * 4);
  float* row_w     = (float*)take((size_t)TT * 2 * 4);
  int*   sel_e     = (int*)take((size_t)TT * 2 * 4);
  float* sel_w     = (float*)take((size_t)TT * 2 * 4);
  if (off > ws_size) return;  // workspace too small — fail loudly via absmax

  hipMemsetAsync(counts, 0, EE * 4, stream);
  hipMemsetAsync(out, 0, (size_t)TT * HH * 4, stream);

  k_gating<<<TT, 256, 0, stream>>>(x, gw, xb, sel_e, sel_w, counts);
  k_fill<<<1, 256, 0, stream>>>(counts, sel_e, sel_w, bases, row_token, row_w);
  k_gemm1<<<dim3(II / 128, 16, EE), 256, 0, stream>>>(xb, w1, hid, counts, bases, row_token);
  k_gemm2<<<dim3(8 * KS, 16, EE), 256, 0, stream>>>(hid, w2, out, counts, bases, row_token, row_w);
}